// Round 13
// baseline (233.249 us; speedup 1.0000x reference)
//
#include <hip/hip_runtime.h>
#include <hip/hip_bf16.h>
#include <math.h>
#include <stdint.h>

// ---------------------------------------------------------------------------
// AttentionLayer B=2,S=2048,D=1024,H=16,Hd=64.  fp32 or bf16 in/out, sniffed
// at runtime.  Pipeline: sniff -> convert -> gemm_qkv -> flash -> gemm_o.
// R22 = R12 (best, 226.3us) + two separable changes:
//  * T1 XCD remap on BOTH GEMM grids.  Theory: GEMM block is TRAFFIC-bound
//    (R6/R7/R8 structure nulls; ~600MB/iter re-fetch: B fp32 panel x32
//    m-blocks, A x8 n-blocks ~ 60-100us at L3 BW).  lin=x+32y spreads
//    same-B blocks over all 8 XCDs -> per-k-step B-chunk re-fetched per
//    XCD.  Remap gemm_qkv: y'=lin&7, x'=lin>>3 (all 32 same-panel blocks
//    on one XCD; step-chunk 16KB L2-hot).  gemm_o: y'=(lin&7)+8*(j>>5),
//    x'=j&31, j=lin>>3 (2 panels/XCD).  Bijective, no math change.
//  * T5 s_setprio(1) around flash's QKT and PV MFMA clusters (waves have
//    role diversity from the T15 pipeline -> scheduler can favor MFMA).
// Flash otherwise byte-identical to R12 (T12+T1+v_exp+T15+xor-swizzle).
// ---------------------------------------------------------------------------

typedef __bf16 bf16x8 __attribute__((ext_vector_type(8)));
typedef float  f32x4  __attribute__((ext_vector_type(4)));
typedef float  f32x8  __attribute__((ext_vector_type(8)));
typedef float  f32x16 __attribute__((ext_vector_type(16)));
typedef unsigned int   u32x4 __attribute__((ext_vector_type(4)));
typedef unsigned short u16x8 __attribute__((ext_vector_type(8)));
typedef unsigned short u16x4 __attribute__((ext_vector_type(4)));
typedef u16x8 u16x8a __attribute__((may_alias));
typedef u16x4 u16x4a __attribute__((may_alias));
typedef f32x8 f32x8a __attribute__((may_alias));
typedef unsigned short u16a __attribute__((may_alias));
typedef float f32a __attribute__((may_alias));

#define BATCH 2
#define SQL   2048
#define DM    1024
#define NH    16
#define HD    64

__device__ __forceinline__ unsigned short f2bf(float f) {
    union { __hip_bfloat16 h; unsigned short u; } cv;
    cv.h = __float2bfloat16(f);
    return cv.u;
}
__device__ __forceinline__ float bf2f(unsigned short u) {
    union { unsigned int i; float f; } cv;
    cv.i = ((unsigned int)u) << 16;
    return cv.f;
}
__device__ __forceinline__ bf16x8 ldfrag(const unsigned short* p) {
    return __builtin_bit_cast(bf16x8, *(const u16x8a*)p);
}
__device__ __forceinline__ void stage8(const void* __restrict__ src, size_t off,
                                       int f32f, unsigned short* dst) {
    if (f32f) {
        f32x8 v = *(const f32x8a*)((const float*)src + off);
        u16x8 o;
#pragma unroll
        for (int i = 0; i < 8; i++) o[i] = f2bf(v[i]);
        *(u16x8a*)dst = o;
    } else {
        *(u16x8a*)dst = *(const u16x8a*)((const unsigned short*)src + off);
    }
}
__device__ __forceinline__ float rdel(const void* p, size_t i, int f) {
    return f ? ((const f32a*)p)[i] : bf2f(((const u16a*)p)[i]);
}
// Async global->LDS, 16 B per lane.  LDS dst is wave-uniform base +
// lane*16 (HW rule); global src is per-lane (enables source pre-swizzle).
__device__ __forceinline__ void gload16(const void* g, void* l) {
    __builtin_amdgcn_global_load_lds(
        (const __attribute__((address_space(1))) unsigned int*)g,
        (__attribute__((address_space(3))) unsigned int*)l,
        16, 0, 0);
}
// v_cvt_pk_bf16_f32: D.lo16 = bf16(lo), D.hi16 = bf16(hi).
__device__ __forceinline__ unsigned int cvtpk(float lo, float hi) {
    unsigned int r;
    asm("v_cvt_pk_bf16_f32 %0, %1, %2" : "=v"(r) : "v"(lo), "v"(hi));
    return r;
}
// Raw v_exp_f32 (exp2): bounded inputs, 1-ULP invisible at bf16 rounding.
__device__ __forceinline__ float fexp2(float x) {
#if __has_builtin(__builtin_amdgcn_exp2f)
    return __builtin_amdgcn_exp2f(x);
#else
    float r;
    asm("v_exp_f32 %0, %1" : "=v"(r) : "v"(x));
    return r;
#endif
}

// ---------------------------------------------------------------------------
// Dtype sniffer: flag = 1 -> fp32 inputs (and fp32 output).
// ---------------------------------------------------------------------------
__global__ void sniff(const void* __restrict__ q, int* __restrict__ flag) {
    __shared__ int cnt;
    if (threadIdx.x == 0) cnt = 0;
    __syncthreads();
    const u16a* p = (const u16a*)q;
    int c = 0;
#pragma unroll
    for (int i = 0; i < 8; i++) {
        unsigned short u = p[threadIdx.x * 8 + i];
        int e = (u >> 7) & 0xFF;
        if (e >= 96 && e <= 159) c++;
    }
    atomicAdd(&cnt, c);
    __syncthreads();
    if (threadIdx.x == 0) *flag = (cnt < 1741) ? 1 : 0;   // 85% of 2048
}

// ---------------------------------------------------------------------------
// Convert pass: fp32 -> bf16.  z 0..2: activations, z 3..6: weights.
// ---------------------------------------------------------------------------
__global__ __launch_bounds__(256)
void convert(const void* s0, const void* s1, const void* s2, const void* s3,
             const void* s4, const void* s5, const void* s6,
             unsigned short* d0, unsigned short* d1, unsigned short* d2,
             unsigned short* d3, unsigned short* d4, unsigned short* d5,
             unsigned short* d6, const int* __restrict__ flag)
{
    if (*flag == 0) return;
    const int z = blockIdx.z;
    const float* s; unsigned short* d; size_t n;
    switch (z) {
        case 0: s = (const float*)s0; d = d0; n = (size_t)BATCH * SQL * DM; break;
        case 1: s = (const float*)s1; d = d1; n = (size_t)BATCH * SQL * DM; break;
        case 2: s = (const float*)s2; d = d2; n = (size_t)BATCH * SQL * DM; break;
        case 3: s = (const float*)s3; d = d3; n = (size_t)DM * DM; break;
        case 4: s = (const float*)s4; d = d4; n = (size_t)DM * DM; break;
        case 5: s = (const float*)s5; d = d5; n = (size_t)DM * DM; break;
        default: s = (const float*)s6; d = d6; n = (size_t)DM * DM; break;
    }
    const size_t stride = (size_t)gridDim.x * blockDim.x * 8;
    for (size_t i = ((size_t)blockIdx.x * blockDim.x + threadIdx.x) * 8; i < n;
         i += stride) {
        f32x8 v = *(const f32x8a*)(s + i);
        u16x8 o;
#pragma unroll
        for (int j = 0; j < 8; j++) o[j] = f2bf(v[j]);
        *(u16x8a*)(d + i) = o;
    }
}

// ---------------------------------------------------------------------------
// GEMM core (R5 structure; block coords passed in for XCD remap):
// C = A[M,K] @ Bt[N,K]^T + bias.  K=N=1024, bf16 MFMA 16x16x32, 128xBN
// tile (BN = 128 or 64), BK=32, 4 waves 2x2, 4xNJ frags.
// oMode: 0 = bf16 row-major, 1 = f32 row-major, 2 = bf16 VT[b][h][d][tok].
// ---------------------------------------------------------------------------
template<int BLDS, int BN>
__device__ __forceinline__ void gemm_core(
    const unsigned short* __restrict__ Abf,
    const unsigned short* __restrict__ Bbf,   // bf16 B (used when BLDS)
    const void* __restrict__ Braw,            // raw B, dtype wF32 (BLDS=0)
    const void* __restrict__ bias, void* __restrict__ Cv,
    float scale, int wF32, int oMode, int bF32, int bx, int by)
{
    constexpr int K = 1024, N = 1024, BK = 32;
    constexpr int NJ = BN / 32;               // B frags per wave
    constexpr int CALLS = BN / 64;            // B gload16 calls per wave
    __shared__ unsigned short Alds[128 * BK];
    __shared__ unsigned short Blds[BN * BK];

    const int t = threadIdx.x;
    const int lane = t & 63, wave = t >> 6;
    const int quad = lane >> 4, r15 = lane & 15;
    const int wm = (wave >> 1) * 64, wn = (wave & 1) * (BN / 2);
    const int m0 = bx * 128, n0 = by * BN;

    f32x4 acc[4][NJ];
#pragma unroll
    for (int i = 0; i < 4; i++)
#pragma unroll
        for (int j = 0; j < NJ; j++) acc[i][j] = (f32x4){0.f, 0.f, 0.f, 0.f};

    const int gr = lane >> 2, gc = lane & 3;
    const unsigned short* gA = Abf + (size_t)(m0 + wave * 32 + gr) * K + gc * 8;
    const unsigned short* gB = Bbf + (size_t)(n0 + wave * 16 * CALLS + gr) * K + gc * 8;
    unsigned short* lA = &Alds[wave * 1024];
    unsigned short* lB = &Blds[wave * 512 * CALLS];
    const int srow = t >> 2, sch = t & 3;
    const size_t offB0 = (size_t)(n0 + srow) * K + sch * 8;
    const size_t offB1 = (size_t)(n0 + 64 + srow) * K + sch * 8;

    for (int k0 = 0; k0 < K; k0 += BK) {
        gload16(gA + k0, lA);
        gload16(gA + k0 + 16 * K, lA + 512);
        if constexpr (BLDS) {
#pragma unroll
            for (int c = 0; c < CALLS; c++)
                gload16(gB + k0 + c * 16 * K, lB + c * 512);
        } else {
            stage8(Braw, offB0 + k0, wF32, &Blds[srow * BK + sch * 8]);
            if constexpr (BN == 128)
                stage8(Braw, offB1 + k0, wF32, &Blds[(64 + srow) * BK + sch * 8]);
        }
        __syncthreads();

        bf16x8 af[4], bfr[NJ];
#pragma unroll
        for (int i = 0; i < 4; i++)
            af[i] = ldfrag(&Alds[(wm + i * 16 + r15) * BK + quad * 8]);
#pragma unroll
        for (int j = 0; j < NJ; j++)
            bfr[j] = ldfrag(&Blds[(wn + j * 16 + r15) * BK + quad * 8]);
#pragma unroll
        for (int i = 0; i < 4; i++)
#pragma unroll
            for (int j = 0; j < NJ; j++)
                acc[i][j] = __builtin_amdgcn_mfma_f32_16x16x32_bf16(af[i], bfr[j], acc[i][j], 0, 0, 0);
        __syncthreads();
    }

    float bvv[NJ];
#pragma unroll
    for (int j = 0; j < NJ; j++)
        bvv[j] = rdel(bias, n0 + wn + j * 16 + r15, bF32);

    if (oMode == 2) {
        // VT[b][h][d][tok]: per fragment, 4 acc rows = 4 contiguous toks.
#pragma unroll
        for (int i = 0; i < 4; i++)
#pragma unroll
            for (int j = 0; j < NJ; j++) {
                int rr = m0 + wm + i * 16 + quad * 4;
                int cc = n0 + wn + j * 16 + r15;
                int bb = rr >> 11, tok = rr & (SQL - 1);
                int hh = cc >> 6,  dd  = cc & (HD - 1);
                u16x4 pk;
#pragma unroll
                for (int r = 0; r < 4; r++) pk[r] = f2bf(acc[i][j][r] + bvv[j]);
                *(u16x4a*)&((u16a*)Cv)[((((size_t)bb * NH + hh) * HD + dd) << 11) + tok] = pk;
            }
    } else {
#pragma unroll
        for (int i = 0; i < 4; i++)
#pragma unroll
            for (int j = 0; j < NJ; j++)
#pragma unroll
                for (int r = 0; r < 4; r++) {
                    int rr = m0 + wm + i * 16 + quad * 4 + r;
                    int cc = n0 + wn + j * 16 + r15;
                    float vv = (acc[i][j][r] + bvv[j]) * scale;
                    if (oMode) ((f32a*)Cv)[(size_t)rr * N + cc] = vv;
                    else       ((u16a*)Cv)[(size_t)rr * N + cc] = f2bf(vv);
                }
    }
}

template<int BLDS>
__global__ __launch_bounds__(256)
void gemm_qkv_k(const void* __restrict__ xq, const void* __restrict__ xk,
                const void* __restrict__ xv,
                const unsigned short* __restrict__ qc,
                const unsigned short* __restrict__ kc,
                const unsigned short* __restrict__ vc,
                const void* __restrict__ Wq, const void* __restrict__ Wk,
                const void* __restrict__ Wv,
                const unsigned short* __restrict__ Wqc,
                const unsigned short* __restrict__ Wkc,
                const unsigned short* __restrict__ Wvc,
                const void* __restrict__ bq, const void* __restrict__ bk,
                const void* __restrict__ bv,
                unsigned short* __restrict__ Qp, unsigned short* __restrict__ Kp,
                unsigned short* __restrict__ Vp,
                float qscale, const int* __restrict__ flag)
{
    const int f = *flag;
    const int z = blockIdx.z;
    // T1: all 32 blocks sharing a B-panel (same y') land on one XCD.
    const int lin = blockIdx.x + 32 * blockIdx.y;
    const int bx = lin >> 3, by = lin & 7;
    const void* xo = (z == 0) ? xq : (z == 1) ? xk : xv;
    const unsigned short* xc = (z == 0) ? qc : (z == 1) ? kc : vc;
    const unsigned short* A = f ? xc : (const unsigned short*)xo;
    const void* Wraw = (z == 0) ? Wq : (z == 1) ? Wk : Wv;
    const unsigned short* Wc = (z == 0) ? Wqc : (z == 1) ? Wkc : Wvc;
    const unsigned short* Bc = (BLDS && f) ? Wc : (const unsigned short*)Wraw;
    const void* bi = (z == 0) ? bq : (z == 1) ? bk : bv;
    unsigned short* C = (z == 0) ? Qp : (z == 1) ? Kp : Vp;
    gemm_core<BLDS, 128>(A, Bc, Wraw, bi, C, (z == 0) ? qscale : 1.0f, f,
                         (z == 2) ? 2 : 0, f, bx, by);
}

template<int BLDS>
__global__ __launch_bounds__(256)
void gemm_o_k(const unsigned short* __restrict__ A, const void* __restrict__ Wo,
              const unsigned short* __restrict__ Woc, const void* __restrict__ bo,
              void* __restrict__ out, const int* __restrict__ flag)
{
    const int f = *flag;
    // T1: 16 B-panels over 8 XCDs -> 2 panels/XCD.
    const int lin = blockIdx.x + 32 * blockIdx.y;
    const int j = lin >> 3;
    const int by = (lin & 7) + 8 * (j >> 5);
    const int bx = j & 31;
    const unsigned short* Bc = (BLDS && f) ? Woc : (const unsigned short*)Wo;
    gemm_core<BLDS, 64>(A, Bc, Wo, bo, out, 1.0f, f, f, f, bx, by);
}

// ---------------------------------------------------------------------------
// Flash attention: 32x32 MFMA + swapped QK^T, in-register softmax (T12),
// XCD remap (T1), v_exp_f32, T15 2-tile pipeline, k^(k>>3) swizzle,
// T5 setprio around MFMA clusters.  Grid (16, 32) = 512 blocks; 4 waves.
// ---------------------------------------------------------------------------
__global__ __launch_bounds__(256)
void flash(const unsigned short* __restrict__ Qp,
           const unsigned short* __restrict__ Kp,
           const unsigned short* __restrict__ VT,
           const int* __restrict__ mask,
           unsigned short* __restrict__ AO)
{
    __shared__ unsigned short Klds[3][64 * 64];   // [key][d], swizzled slots
    __shared__ unsigned short Vlds[3][64 * 64];   // [d][key], swizzled slots

    const int t = threadIdx.x, wave = t >> 6, lane = t & 63;
    const int hi = lane >> 5, l31 = lane & 31;
    // read-side XOR keys: k(row) = (row ^ (row>>3)) & 7; row 32+l31 -> ^4
    const int kq0 = (l31 ^ (l31 >> 3)) & 7;
    const int kq1 = kq0 ^ 4;
    // T1 XCD remap: lin%8 constant per bh-group -> same XCD (bijective).
    const int lin = blockIdx.x + 16 * blockIdx.y;
    const int xcd = lin & 7, jj = lin >> 3;
    const int bh = xcd + 8 * (jj >> 4);
    const int qt = jj & 15;
    const int b = bh >> 4, h = bh & 15;
    const size_t base = (size_t)b * SQL * DM + (size_t)h * HD;

    // ---- staging geometry: per wave 2 K-calls + 2 V-calls ----
    const int srow8 = lane >> 3, sc8 = lane & 7;
    const unsigned short* gK[2];
    const unsigned short* gV[2];
    int ldof[2];
#pragma unroll
    for (int i = 0; i < 2; i++) {
        const int row = wave * 16 + i * 8 + srow8;     // key (K) / d (V)
        const int slot = sc8 ^ ((row ^ (row >> 3)) & 7);  // inverse swizzle
        gK[i] = Kp + base + (size_t)row * DM + slot * 8;
        gV[i] = VT + (((size_t)(b * NH + h) * HD + row) << 11) + slot * 8;
        ldof[i] = (wave * 16 + i * 8) * 64;            // wave-uniform LDS base
    }

    // ---- Q B-frags: n=qrow=l31 (wave's 32 rows), k = c*16 + hi*8 + j ----
    const int qrow = qt * 128 + wave * 32 + l31;
    bf16x8 qf[4];
#pragma unroll
    for (int c = 0; c < 4; c++)
        qf[c] = ldfrag(&Qp[base + (size_t)qrow * DM + c * 16 + hi * 8]);

    f32x16 o0 = {}, o1 = {};
    float l_acc = 0.f;

    auto STAGE = [&](int tile, int bi) {
#pragma unroll
        for (int i = 0; i < 2; i++) {
            gload16(gK[i] + (size_t)tile * 64 * DM, &Klds[bi][ldof[i]]);
            gload16(gV[i] + tile * 64,              &Vlds[bi][ldof[i]]);
        }
    };
    auto QKT = [&](int bi, f32x16& S0, f32x16& S1) {
        __builtin_amdgcn_s_setprio(1);
#pragma unroll
        for (int c = 0; c < 4; c++) {
            const int ch = c * 2 + hi;
            bf16x8 kf0 = ldfrag(&Klds[bi][l31 * 64 + ((ch ^ kq0) << 3)]);
            bf16x8 kf1 = ldfrag(&Klds[bi][(32 + l31) * 64 + ((ch ^ kq1) << 3)]);
            S0 = __builtin_amdgcn_mfma_f32_32x32x16_bf16(kf0, qf[c], S0, 0, 0, 0);
            S1 = __builtin_amdgcn_mfma_f32_32x32x16_bf16(kf1, qf[c], S1, 0, 0, 0);
        }
        __builtin_amdgcn_s_setprio(0);
    };
    auto SMPV = [&](f32x16& S0, f32x16& S1, int bi, unsigned long long bal) {
#pragma unroll
        for (int r = 0; r < 16; r++) {
            S0[r] = fexp2(S0[r]);
            S1[r] = fexp2(S1[r]);
        }
        if (__builtin_expect(bal != 0ull, 0)) {        // slow path: zero masked
            const unsigned int m0 = ((unsigned int)bal) >> (4 * hi);
            const unsigned int m1 = ((unsigned int)(bal >> 32)) >> (4 * hi);
#pragma unroll
            for (int r = 0; r < 16; r++) {
                const int bp = ((r >> 2) << 3) + (r & 3);
                if ((m0 >> bp) & 1) S0[r] = 0.f;
                if ((m1 >> bp) & 1) S1[r] = 0.f;
            }
        }
#pragma unroll
        for (int r = 0; r < 16; r++) l_acc += S0[r] + S1[r];
        __builtin_amdgcn_s_setprio(1);
#pragma unroll
        for (int c = 0; c < 4; c++) {
            const int qb = 2 * (c & 1);
            unsigned int x0, x1, y0, y1;
            if (c < 2) {
                x0 = cvtpk(S0[4 * qb + 0], S0[4 * qb + 1]);
                x1 = cvtpk(S0[4 * qb + 2], S0[4 * qb + 3]);
                y0 = cvtpk(S0[4 * qb + 4], S0[4 * qb + 5]);
                y1 = cvtpk(S0[4 * qb + 6], S0[4 * qb + 7]);
            } else {
                x0 = cvtpk(S1[4 * qb + 0], S1[4 * qb + 1]);
                x1 = cvtpk(S1[4 * qb + 2], S1[4 * qb + 3]);
                y0 = cvtpk(S1[4 * qb + 4], S1[4 * qb + 5]);
                y1 = cvtpk(S1[4 * qb + 6], S1[4 * qb + 7]);
            }
            asm volatile("v_permlane32_swap_b32 %0, %1" : "+v"(x0), "+v"(y0));
            asm volatile("v_permlane32_swap_b32 %0, %1" : "+v"(x1), "+v"(y1));
            u32x4 w = {x0, x1, y0, y1};
            bf16x8 pa = __builtin_bit_cast(bf16x8, w);

            const int ch = c * 2 + hi;
            bf16x8 v0 = ldfrag(&Vlds[bi][l31 * 64 + ((ch ^ kq0) << 3)]);
            bf16x8 v1 = ldfrag(&Vlds[bi][(32 + l31) * 64 + ((ch ^ kq1) << 3)]);
            o0 = __builtin_amdgcn_mfma_f32_32x32x16_bf16(pa, v0, o0, 0, 0, 0);
            o1 = __builtin_amdgcn_mfma_f32_32x32x16_bf16(pa, v1, o1, 0, 0, 0);
        }
        __builtin_amdgcn_s_setprio(0);
    };

    constexpr int NT = SQL / 64;
    // ---- prologue: stage 0; wait; stage 1; QK(0) ----
    STAGE(0, 0);
    __syncthreads();
    STAGE(1, 1);
    int mkC = mask[b * SQL + lane];               // tile 0
    f32x16 sA0 = {}, sA1 = {}, sB0 = {}, sB1 = {};
    QKT(0, sA0, sA1);

    for (int tt = 0; tt < NT; tt += 2) {
        // ---- even: cur = sA (tile tt), next = sB (tile tt+1) ----
        __syncthreads();                          // drains stage(tt+1)
        if (tt + 2 < NT) STAGE(tt + 2, (tt + 2) % 3);
        int mkN = (tt + 1 < NT) ? mask[b * SQL + (tt + 1) * 64 + lane] : 0;
        if (tt + 1 < NT) {
            sB0 = 0.f; sB1 = 0.f;
            QKT((tt + 1) % 3, sB0, sB1);          // matrix pipe ...
        }
        unsigned long long bal = __ballot(mkC != 0);
        SMPV(sA0, sA1, tt % 3, bal);              // ... overlaps VALU softmax
        mkC = mkN;
        // ---- odd: cur = sB (tile tt+1), next = sA (tile tt+2) ----
        __syncthreads();                          // drains stage(tt+2)
        if (tt + 3 < NT) STAGE(tt + 3, (tt + 3) % 3);
        mkN = (tt + 2 < NT) ? mask[b * SQL + (tt + 2) * 64 + lane] : 0;
        if (tt + 2 < NT) {
            sA0 = 0.f; sA1 = 0.f;
            QKT((tt + 2) % 3, sA0, sA1);
        }
        bal = __ballot(mkC != 0);
        SMPV(sB0, sB1, (tt + 1) % 3, bal);
        mkC = mkN;
    }

    // ---- l: lane's qrow sum = own half + partner half ----
    const float l_tot = l_acc + __shfl_xor(l_acc, 32, 64);
    const float linv = (l_tot > 0.f) ? 1.0f / l_tot : 0.f;  // for qrow=l31

    // ---- epilogue: O / l -> bf16 ws at (b, row, h*64 + d) ----
#pragma unroll
    for (int r = 0; r < 16; r++) {
        const int ql = (r & 3) + ((r >> 2) << 3) + 4 * hi;   // local qrow
        const float ls = __shfl(linv, ql, 64);
        const int row = qt * 128 + wave * 32 + ql;
        AO[base + (size_t)row * DM + l31]      = f2bf(o0[r] * ls);
        AO[base + (size_t)row * DM + 32 + l31] = f2bf(o1[r] * ls);
    }
}

// ---------------------------------------------------------------------------
extern "C" void kernel_launch(void* const* d_in, const int* in_sizes, int n_in,
                              void* d_out, int out_size, void* d_ws, size_t ws_size,
                              hipStream_t stream)
{
    (void)in_sizes; (void)n_in; (void)out_size;

    const void* q    = d_in[0];
    const void* k    = d_in[1];
    const void* v    = d_in[2];
    const int*  mask = (const int*)d_in[3];
    const void* Wq   = d_in[4];
    const void* bq   = d_in[5];
    const void* Wk   = d_in[6];
    const void* bk   = d_in[7];
    const void* Wv   = d_in[8];
    const void* bv   = d_in[9];
    const void* Wo   = d_in[10];
    const void* bo   = d_in[11];

    const size_t ACT = (size_t)BATCH * SQL * DM;   // 4M elems (8 MB bf16)
    const size_t WE  = (size_t)DM * DM;            // 1M elems (2 MB bf16)
    int* flag = (int*)d_ws;                        // 512 B header
    unsigned short* Qp = (unsigned short*)((char*)d_ws + 512);
    unsigned short* Kp = Qp + ACT;
    unsigned short* Vp = Kp + ACT;                 // holds VT[b][h][d][tok]
    unsigned short* AO = Vp + ACT;                 // 32 MB + 512 B baseline

    const size_t needFull = 512 + (4 * ACT + 3 * ACT + 4 * WE) * 2;
    const size_t needMid  = 512 + (4 * ACT + 4 * WE) * 2;
    const int tier = (ws_size >= needFull) ? 2 : (ws_size >= needMid) ? 1 : 0;

    unsigned short* qc;
    unsigned short* kc;
    unsigned short* vc;
    unsigned short* Wqc = AO + ACT;                // ws past baseline
    unsigned short* Wkc = Wqc + WE;
    unsigned short* Wvc = Wkc + WE;
    unsigned short* Woc = Wvc + WE;
    if (tier == 2) {
        qc = Woc + WE;
        kc = qc + ACT;
        vc = kc + ACT;
    } else {
        qc = AO;                                   // dead until flash writes
        kc = (unsigned short*)d_out;               // dead until gemm_o writes
        vc = kc + ACT;
    }

    // Fold 1/sqrt(64) and log2(e) into Q so flash uses exp2 directly.
    const float QSCALE = 0.125f * 1.44269504088896340736f;

    sniff<<<1, 256, 0, stream>>>(q, flag);
    if (tier >= 1) {
        convert<<<dim3(256, 1, 7), 256, 0, stream>>>(
            q, k, v, Wq, Wk, Wv, Wo, qc, kc, vc, Wqc, Wkc, Wvc, Woc, flag);
        gemm_qkv_k<1><<<dim3(32, 8, 3), 256, 0, stream>>>(
            q, k, v, qc, kc, vc, Wq, Wk, Wv, Wqc, Wkc, Wvc,
            bq, bk, bv, Qp, Kp, Vp, QSCALE, flag);
    } else {
        convert<<<dim3(256, 1, 3), 256, 0, stream>>>(
            q, k, v, nullptr, nullptr, nullptr, nullptr,
            qc, kc, vc, nullptr, nullptr, nullptr, nullptr, flag);
        gemm_qkv_k<0><<<dim3(32, 8, 3), 256, 0, stream>>>(
            q, k, v, qc, kc, vc, Wq, Wk, Wv, nullptr, nullptr, nullptr,
            bq, bk, bv, Qp, Kp, Vp, QSCALE, flag);
    }
    flash<<<dim3(SQL / 128, BATCH * NH), 256, 0, stream>>>(Qp, Kp, Vp, mask, AO);
    if (tier >= 1)
        gemm_o_k<1><<<dim3(32, 16), 256, 0, stream>>>(AO, Wo, Woc, bo, d_out, flag);
    else
        gemm_o_k<0><<<dim3(32, 16), 256, 0, stream>>>(AO, Wo, nullptr, bo, d_out, flag);
}